// Round 2
// baseline (825.556 us; speedup 1.0000x reference)
//
#include <hip/hip_runtime.h>
#include <hip/hip_bf16.h>
#include <stdint.h>

typedef _Float16 f16;
typedef __attribute__((ext_vector_type(8))) _Float16 half8;
typedef __attribute__((ext_vector_type(4))) float f32x4;

typedef __attribute__((address_space(1))) void gvoid_t;
typedef __attribute__((address_space(3))) void lvoid_t;

// HBM -> LDS DMA, 16 B per lane. LDS dest is wave-uniform base + lane*16.
__device__ __forceinline__ void dma16(const void* g, void* l) {
    __builtin_amdgcn_global_load_lds((gvoid_t*)g, (lvoid_t*)l, 16, 0, 0);
}

// ---------------------------------------------------------------------------
// P1: transpose + cast x [8,4096,256] f32 -> xT [8,256,4096] f16
// grid (64, 4, 8), block 256
// ---------------------------------------------------------------------------
__global__ void __launch_bounds__(256) transpose_x_kernel(
    const float* __restrict__ x, f16* __restrict__ xT)
{
    __shared__ __align__(16) f16 tile[64][72];
    int b  = blockIdx.z;
    int m0 = blockIdx.x * 64;
    int d0 = blockIdx.y * 64;
    const float* xb = x + (size_t)b * 4096 * 256;
    f16* xTb = xT + (size_t)b * 256 * 4096;
    int tid = threadIdx.x;
    int c4 = tid & 15;
    int rb = tid >> 4;
#pragma unroll
    for (int p = 0; p < 4; ++p) {
        int row = p * 16 + rb;
        float4 v = *(const float4*)(xb + (size_t)(m0 + row) * 256 + d0 + c4 * 4);
        tile[c4 * 4 + 0][row] = (f16)v.x;
        tile[c4 * 4 + 1][row] = (f16)v.y;
        tile[c4 * 4 + 2][row] = (f16)v.z;
        tile[c4 * 4 + 3][row] = (f16)v.w;
    }
    __syncthreads();
    int mseg = tid & 7;
    int db = tid >> 3;
#pragma unroll
    for (int p = 0; p < 2; ++p) {
        int dd = p * 32 + db;
        uint4 val = *(const uint4*)&tile[dd][mseg * 8];
        *(uint4*)(xTb + (size_t)(d0 + dd) * 4096 + m0 + mseg * 8) = val;
    }
}

// ---------------------------------------------------------------------------
// P2: weight transposes to n-major f16
// ---------------------------------------------------------------------------
__global__ void __launch_bounds__(256) prep_weights_kernel(
    const float* __restrict__ W1, const float* __restrict__ W2,
    f16* __restrict__ W1T, f16* __restrict__ W2T)
{
    int idx = blockIdx.x * 256 + threadIdx.x;
    if (idx < 131072) {
        int n = idx >> 8;
        int k = idx & 255;
        W1T[idx] = (f16)W1[k * 512 + n];
    } else {
        int j = idx - 131072;
        int d = j >> 9;
        int hh = j & 511;
        W2T[j] = (f16)W2[hh * 256 + d];
    }
}

// ---------------------------------------------------------------------------
// K1 (FUSED): out = relu((1+eps)*x + adj@x) @ W1 ... @ W2 + biases.
// Main loop identical to verified round-1 bmm:
//   grid 256 blocks (1/CU), 512 threads (8 waves: 4m x 2n, wave tile 32x128)
//   BM=128, BN=256 (full d), BK=32, 128 K-iters, batch = bid&7 (XCD affinity),
//   4 LDS buffers, depth-2 prefetch, counted vmcnt, one s_barrier/iter.
// Epilogue fusion (new):
//   E1: h-tile (128x256) -> f16 LDS (aliased over A-buffers), XOR-swizzled.
//   E2: 4 chunks of 128 hidden cols:
//       GEMM2 (K=256): A from h_lds, B streamed from L2-resident W1T
//       bias+relu -> 32 KB chunk buf (2 bufs, 1 barrier/chunk)
//       GEMM3 partial (K-chunk=128): A from chunk buf, B from W2T,
//       accumulate into reused 64-VGPR out accumulator.
//   E3: + b2, f32 store. Eliminates h/hidden round-trips + 2 launches.
// ---------------------------------------------------------------------------
__device__ __forceinline__ void bmm_dma_tile(
    const float* adjb, const f16* xTb, float* AsBuf, f16* BsBuf,
    int kk, int wid, int lane)
{
    // A tile: 128 rows x 32 f32 (16 KB) = 16 chunks of 8 rows; wave w: w, w+8
    int a_rr = lane >> 3, a_sl = lane & 7;
#pragma unroll
    for (int c = 0; c < 2; ++c) {
        int chunk = wid + c * 8;
        int r = chunk * 8 + a_rr;
        int colg = a_sl ^ ((r & 7) ^ ((r >> 3) & 1));   // swizzle slot of 4 floats
        dma16(adjb + (size_t)r * 4096 + kk + colg * 4, AsBuf + chunk * 256);
    }
    // B tile: 256 rows x 32 f16 (16 KB) = 16 chunks of 16 rows; wave w: w, w+8
    int b_rr = lane >> 2, b_sl = lane & 3;
#pragma unroll
    for (int c = 0; c < 2; ++c) {
        int chunk = wid + c * 8;
        int r = chunk * 16 + b_rr;
        int colg = b_sl ^ ((r & 3) ^ ((r >> 2) & 3));   // swizzle slot of 8 f16
        dma16(xTb + (size_t)r * 4096 + kk + colg * 8, BsBuf + chunk * 512);
    }
}

__global__ void __launch_bounds__(512) fused_kernel(
    const float* __restrict__ adj, const f16* __restrict__ xT,
    const float* __restrict__ x, const float* __restrict__ eps,
    const f16* __restrict__ W1T, const float* __restrict__ b1,
    const f16* __restrict__ W2T, const float* __restrict__ b2,
    float* __restrict__ out)
{
    // 128 KB LDS, aliased between main loop and epilogue:
    //   main:   As[4] @ 0..64K (4x16KB f32), Bs[4] @ 64K..128K (4x16KB f16)
    //   epi:    h_lds (64 KB)  @ 0..64K, hid bufs 2x32 KB @ 64K..128K
    __shared__ __align__(16) unsigned char smem[131072];
    float* AsBase = (float*)smem;
    f16*   BsBase = (f16*)(smem + 65536);

    const int lin = blockIdx.x;
    const int b   = lin & 7;            // batch -> XCD affinity (round-robin by 8)
    const int m0  = (lin >> 3) * 128;
    const int tid = threadIdx.x;
    const int lane = tid & 63, wid = tid >> 6;
    const int wm = (wid & 3) * 32;      // 4 wave-rows of 32
    const int wn = (wid >> 2) * 128;    // 2 wave-cols of 128
    const int l15 = lane & 15, lg = lane >> 4;

    const float* adjb = adj + (size_t)b * 4096 * 4096 + (size_t)m0 * 4096;
    const f16*   xTb  = xT  + (size_t)b * 256 * 4096;

    f32x4 acc[2][8];
#pragma unroll
    for (int i = 0; i < 2; ++i)
#pragma unroll
        for (int j = 0; j < 8; ++j) { f32x4 z = {0.f, 0.f, 0.f, 0.f}; acc[i][j] = z; }

    // prologue: DMA tiles 0 and 1 (depth-2 pipeline)
    bmm_dma_tile(adjb, xTb, AsBase, BsBase, 0, wid, lane);
    bmm_dma_tile(adjb, xTb, AsBase + 4096, BsBase + 8192, 32, wid, lane);

    // frag-read swizzle factors (depend only on l15; tile bases are x16 aligned)
    const int sA = (l15 & 7) ^ (l15 >> 3);
    const int sB = (l15 & 3) ^ ((l15 >> 2) & 3);

    for (int it = 0; it < 128; ++it) {
        // issue tile it+2 (4 vmem instrs per wave: A,A,B,B)
        if (it + 2 < 128) {
            int nb = (it + 2) & 3;
            bmm_dma_tile(adjb, xTb, AsBase + nb * 4096, BsBase + nb * 8192,
                         (it + 2) * 32, wid, lane);
        }

        // counted wait: tile `it`'s 4 loads done; it+1/it+2 stay in flight
        if (it < 126)       asm volatile("s_waitcnt vmcnt(8)" ::: "memory");
        else if (it == 126) asm volatile("s_waitcnt vmcnt(4)" ::: "memory");
        else                asm volatile("s_waitcnt vmcnt(0)" ::: "memory");
        __builtin_amdgcn_s_barrier();            // all waves: tile `it` landed
        asm volatile("" ::: "memory");           // pin LDS reads below barrier

        const float* Ab = AsBase + (it & 3) * 4096;
        const f16*  Bb  = BsBase + (it & 3) * 8192;
        half8 af[2];
#pragma unroll
        for (int mt = 0; mt < 2; ++mt) {
            int R = wm + mt * 16 + l15;
            int p0 = (2 * lg) ^ sA;
            f32x4 a0 = *(const f32x4*)&Ab[R * 32 + p0 * 4];
            f32x4 a1 = *(const f32x4*)&Ab[R * 32 + (p0 ^ 1) * 4];
            half8 t;
            t[0] = (f16)a0.x; t[1] = (f16)a0.y; t[2] = (f16)a0.z; t[3] = (f16)a0.w;
            t[4] = (f16)a1.x; t[5] = (f16)a1.y; t[6] = (f16)a1.z; t[7] = (f16)a1.w;
            af[mt] = t;
        }
        half8 bfr[8];
        const int slotB = lg ^ sB;
#pragma unroll
        for (int nt = 0; nt < 8; ++nt) {
            int C = wn + nt * 16 + l15;
            bfr[nt] = *(const half8*)&Bb[C * 32 + slotB * 8];
        }
#pragma unroll
        for (int mt = 0; mt < 2; ++mt)
#pragma unroll
            for (int nt = 0; nt < 8; ++nt)
                acc[mt][nt] = __builtin_amdgcn_mfma_f32_16x16x32_f16(af[mt], bfr[nt], acc[mt][nt], 0, 0, 0);
    }

    // =======================================================================
    // Fused MLP epilogue
    // =======================================================================
    __syncthreads();   // all waves done reading main-loop LDS (vmcnt already 0)

    // ---- E1: h = (1+eps)*x + acc -> f16 h_lds [128][256], slot-swizzled.
    // acc C/D mapping: row = wm + mt*16 + lg*4 + i, col(d) = wn + nt*16 + l15.
    // swizzle: phys_slot = (d>>3) ^ (R&7); slot = 8 f16 = 16 B.
    {
        float scale = 1.0f + eps[0];
        const float* xb = x + (size_t)b * 4096 * 256;
        f16* h_lds = (f16*)smem;
#pragma unroll
        for (int mt = 0; mt < 2; ++mt) {
#pragma unroll
            for (int i = 0; i < 4; ++i) {
                int R = wm + mt * 16 + lg * 4 + i;
                const float* xrow = xb + (size_t)(m0 + R) * 256;
#pragma unroll
                for (int nt = 0; nt < 8; ++nt) {
                    int d = wn + nt * 16 + l15;
                    float hv = scale * xrow[d] + acc[mt][nt][i];
                    int ps = (d >> 3) ^ (R & 7);
                    h_lds[R * 256 + ps * 8 + (d & 7)] = (f16)hv;
                }
            }
        }
    }
    __syncthreads();

    // reuse acc as the final-output accumulator
#pragma unroll
    for (int i = 0; i < 2; ++i)
#pragma unroll
        for (int j = 0; j < 8; ++j) { f32x4 z = {0.f, 0.f, 0.f, 0.f}; acc[i][j] = z; }

    const f16* h_lds = (const f16*)smem;
    const int wm2 = (wid & 3) * 32;   // GEMM2 wave tile 32x64 over 128x128 chunk
    const int wn2 = (wid >> 2) * 64;

    for (int c = 0; c < 4; ++c) {
        // ---- GEMM2 chunk: hidden[:, c*128 .. +128) = relu(h @ W1 + b1)
        f32x4 acc2[2][4];
#pragma unroll
        for (int i = 0; i < 2; ++i)
#pragma unroll
            for (int j = 0; j < 4; ++j) { f32x4 z = {0.f, 0.f, 0.f, 0.f}; acc2[i][j] = z; }

#pragma unroll 2
        for (int it2 = 0; it2 < 8; ++it2) {
            half8 af2[2], bf2[4];
#pragma unroll
            for (int mt = 0; mt < 2; ++mt) {
                int R = wm2 + mt * 16 + l15;
                int ps = (it2 * 4 + lg) ^ (R & 7);
                af2[mt] = *(const half8*)&h_lds[R * 256 + ps * 8];
            }
#pragma unroll
            for (int nt = 0; nt < 4; ++nt) {
                int n = c * 128 + wn2 + nt * 16 + l15;
                bf2[nt] = *(const half8*)&W1T[(size_t)n * 256 + it2 * 32 + lg * 8];
            }
#pragma unroll
            for (int mt = 0; mt < 2; ++mt)
#pragma unroll
                for (int nt = 0; nt < 4; ++nt)
                    acc2[mt][nt] = __builtin_amdgcn_mfma_f32_16x16x32_f16(af2[mt], bf2[nt], acc2[mt][nt], 0, 0, 0);
        }

        // bias + relu + store chunk (swizzled, same scheme; 16 slots/row)
        f16* hid = (f16*)(smem + 65536 + (c & 1) * 32768);
#pragma unroll
        for (int mt = 0; mt < 2; ++mt) {
#pragma unroll
            for (int i = 0; i < 4; ++i) {
                int R = wm2 + mt * 16 + lg * 4 + i;
#pragma unroll
                for (int nt = 0; nt < 4; ++nt) {
                    int dc = wn2 + nt * 16 + l15;          // col within chunk
                    float v = acc2[mt][nt][i] + b1[c * 128 + dc];
                    v = v > 0.f ? v : 0.f;
                    int ps = (dc >> 3) ^ (R & 7);
                    hid[R * 128 + ps * 8 + (dc & 7)] = (f16)v;
                }
            }
        }
        __syncthreads();   // chunk visible; prior-chunk readers already drained

        // ---- GEMM3 partial: acc += hid_chunk @ W2[c*128 .. , :]
        const f16* hidr = (const f16*)(smem + 65536 + (c & 1) * 32768);
#pragma unroll
        for (int it3 = 0; it3 < 4; ++it3) {
            half8 af3[2], bf3[8];
#pragma unroll
            for (int mt = 0; mt < 2; ++mt) {
                int R = wm + mt * 16 + l15;
                int ps = (it3 * 4 + lg) ^ (R & 7);
                af3[mt] = *(const half8*)&hidr[R * 128 + ps * 8];
            }
#pragma unroll
            for (int nt = 0; nt < 8; ++nt) {
                int dcol = wn + nt * 16 + l15;
                bf3[nt] = *(const half8*)&W2T[(size_t)dcol * 512 + c * 128 + it3 * 32 + lg * 8];
            }
#pragma unroll
            for (int mt = 0; mt < 2; ++mt)
#pragma unroll
                for (int nt = 0; nt < 8; ++nt)
                    acc[mt][nt] = __builtin_amdgcn_mfma_f32_16x16x32_f16(af3[mt], bf3[nt], acc[mt][nt], 0, 0, 0);
        }
    }

    // ---- E3: + b2, f32 store
    {
        float* ob = out + ((size_t)b * 4096 + m0) * 256;
#pragma unroll
        for (int mt = 0; mt < 2; ++mt) {
#pragma unroll
            for (int i = 0; i < 4; ++i) {
                int R = wm + mt * 16 + lg * 4 + i;
#pragma unroll
                for (int nt = 0; nt < 8; ++nt) {
                    int col = wn + nt * 16 + l15;
                    ob[(size_t)R * 256 + col] = acc[mt][nt][i] + b2[col];
                }
            }
        }
    }
}

// ---------------------------------------------------------------------------
// launch
// ---------------------------------------------------------------------------
extern "C" void kernel_launch(void* const* d_in, const int* in_sizes, int n_in,
                              void* d_out, int out_size, void* d_ws, size_t ws_size,
                              hipStream_t stream) {
    (void)in_sizes; (void)n_in; (void)out_size; (void)ws_size;
    const float* x   = (const float*)d_in[0];
    const float* adj = (const float*)d_in[1];
    const float* eps = (const float*)d_in[2];
    const float* W1  = (const float*)d_in[3];
    const float* b1  = (const float*)d_in[4];
    const float* W2  = (const float*)d_in[5];
    const float* b2  = (const float*)d_in[6];
    float* out = (float*)d_out;

    char* ws = (char*)d_ws;
    f16* xT  = (f16*)(ws);                           // 16 MiB
    f16* W1T = (f16*)(ws + (16u << 20));             // 256 KiB
    f16* W2T = (f16*)(ws + (16u << 20) + 262144u);   // 256 KiB

    transpose_x_kernel<<<dim3(64, 4, 8), dim3(256), 0, stream>>>(x, xT);
    prep_weights_kernel<<<dim3(1024), dim3(256), 0, stream>>>(W1, W2, W1T, W2T);
    fused_kernel<<<dim3(256), dim3(512), 0, stream>>>(adj, xT, x, eps,
                                                      W1T, b1, W2T, b2, out);
}